// Round 1
// baseline (358.561 us; speedup 1.0000x reference)
//
#include <hip/hip_runtime.h>

typedef __bf16  bf16x8 __attribute__((ext_vector_type(8)));
typedef float   f32x16 __attribute__((ext_vector_type(16)));

#define NP    31744   /* padded n: 32 b * 31 p * 32 q  (q=31 is a dead pad lane) */
#define NROWS 992     /* 32 b * 31 p */

__device__ __forceinline__ unsigned short f2bf(float f) {
    union { float f; unsigned int u; } v; v.f = f;
    unsigned int r = (v.u + 0x7fffu + ((v.u >> 16) & 1u)) >> 16;
    return (unsigned short)r;
}

// ---------------------------------------------------------------------------
// Kernel A: weight transform U = G g G^T, stored bf16 in MFMA B-fragment order:
//   Up[((ad*16 + cg)*256 + k)*8 + j]   where c = cg*8 + j
// ---------------------------------------------------------------------------
__global__ void wino_wtrans(const float* __restrict__ w, unsigned short* __restrict__ Up) {
    int k = blockIdx.x;        // 0..255
    int c = threadIdx.x;       // 0..127
    const float* g = w + (k * 128 + c) * 9;
    float g00=g[0],g01=g[1],g02=g[2],g10=g[3],g11=g[4],g12=g[5],g20=g[6],g21=g[7],g22=g[8];
    // T = G * g  (4x3)
    float T[4][3];
    T[0][0]=g00;                    T[0][1]=g01;                    T[0][2]=g02;
    T[1][0]=0.5f*(g00+g10+g20);     T[1][1]=0.5f*(g01+g11+g21);     T[1][2]=0.5f*(g02+g12+g22);
    T[2][0]=0.5f*(g00-g10+g20);     T[2][1]=0.5f*(g01-g11+g21);     T[2][2]=0.5f*(g02-g12+g22);
    T[3][0]=g20;                    T[3][1]=g21;                    T[3][2]=g22;
    int cg = c >> 3, j = c & 7;
    #pragma unroll
    for (int a = 0; a < 4; ++a) {
        float u0 = T[a][0];
        float u1 = 0.5f*(T[a][0]+T[a][1]+T[a][2]);
        float u2 = 0.5f*(T[a][0]-T[a][1]+T[a][2]);
        float u3 = T[a][2];
        float uu[4] = {u0,u1,u2,u3};
        #pragma unroll
        for (int d = 0; d < 4; ++d) {
            Up[(((size_t)((a*4+d)*16 + cg))*256 + k)*8 + j] = f2bf(uu[d]);
        }
    }
}

// ---------------------------------------------------------------------------
// Kernel B: input transform V = Bt d Bt^T, stored bf16 in MFMA A-fragment order:
//   Vp[((ad*16 + cg)*NP + n)*8 + j]    where c = cg*8 + j, n = (b*31+p)*32 + q
// Thread map: t = n_local*8 + j  ->  per-(ad,cg) writes are consecutive 2B/lane.
// ---------------------------------------------------------------------------
__global__ __launch_bounds__(256) void wino_itrans(const float* __restrict__ x,
                                                   unsigned short* __restrict__ Vp) {
    int t  = threadIdx.x;
    int j  = t & 7;
    int nl = t >> 3;           // 0..31 == q
    int nb = blockIdx.x;       // 0..991  (= b*31 + p)
    int cg = blockIdx.y;       // 0..15
    int c  = cg * 8 + j;
    int n1 = nb * 32 + nl;
    int b  = nb / 31, p = nb % 31;
    int q  = nl;

    float V[4][4];
    if (q >= 31) {
        #pragma unroll
        for (int a = 0; a < 4; ++a)
            #pragma unroll
            for (int d = 0; d < 4; ++d) V[a][d] = 0.f;
    } else {
        const float* xp = x + ((((size_t)b*128 + c)*64) + 2*p)*64 + 2*q;
        float dd[4][4];
        #pragma unroll
        for (int i = 0; i < 4; ++i) {
            float2 u0 = *(const float2*)(xp + i*64);
            float2 u1 = *(const float2*)(xp + i*64 + 2);
            dd[i][0]=u0.x; dd[i][1]=u0.y; dd[i][2]=u1.x; dd[i][3]=u1.y;
        }
        float s[4][4];
        #pragma unroll
        for (int jj = 0; jj < 4; ++jj) {
            s[0][jj] = dd[0][jj] - dd[2][jj];
            s[1][jj] = dd[1][jj] + dd[2][jj];
            s[2][jj] = dd[2][jj] - dd[1][jj];
            s[3][jj] = dd[1][jj] - dd[3][jj];
        }
        #pragma unroll
        for (int a = 0; a < 4; ++a) {
            V[a][0] = s[a][0] - s[a][2];
            V[a][1] = s[a][1] + s[a][2];
            V[a][2] = s[a][2] - s[a][1];
            V[a][3] = s[a][1] - s[a][3];
        }
    }
    #pragma unroll
    for (int a = 0; a < 4; ++a)
        #pragma unroll
        for (int d = 0; d < 4; ++d)
            Vp[(((size_t)((a*4+d)*16 + cg))*NP + n1)*8 + j] = f2bf(V[a][d]);
}

// ---------------------------------------------------------------------------
// Kernel C: 16 fused GEMMs (M_ad = V_ad^T U_ad over c=128) + inverse transform
// folded incrementally into 4 Y accumulators (At entries are 0/+-1), + bias,
// direct store. Wave tile: 32 n x 32 k, block = 2 n-rows x 2 k-tiles.
// ---------------------------------------------------------------------------
__global__ __launch_bounds__(256, 2) void wino_gemm(
        const unsigned short* __restrict__ Vp, const unsigned short* __restrict__ Up,
        const float* __restrict__ bias, float* __restrict__ out)
{
    const bf16x8* V8 = (const bf16x8*)Vp;
    const bf16x8* U8 = (const bf16x8*)Up;
    int t    = threadIdx.x;
    int lane = t & 63;
    int wave = t >> 6;
    int l31  = lane & 31, q2 = lane >> 5;
    int wn   = wave & 1,  wk = wave >> 1;
    int row  = blockIdx.x * 2 + wn;          // 0..991 = b*31 + p
    int k0   = blockIdx.y * 64 + wk * 32;    // output-channel tile
    int n0   = row * 32;

    const int aOff = q2 * NP  + n0 + l31;    // + (ad*16 + cb*2)*NP
    const int bOff = q2 * 256 + k0 + l31;    // + (ad*16 + cb*2)*256

    f32x16 Y00, Y01, Y10, Y11;
    #pragma unroll
    for (int z = 0; z < 16; ++z) { Y00[z]=0.f; Y01[z]=0.f; Y10[z]=0.f; Y11[z]=0.f; }

    #pragma unroll
    for (int ad = 0; ad < 16; ++ad) {
        f32x16 m;
        #pragma unroll
        for (int z = 0; z < 16; ++z) m[z] = 0.f;
        #pragma unroll
        for (int cb = 0; cb < 8; ++cb) {
            bf16x8 av = V8[(size_t)(ad*16 + cb*2)*NP  + aOff];
            bf16x8 bv = U8[(size_t)(ad*16 + cb*2)*256 + bOff];
            m = __builtin_amdgcn_mfma_f32_32x32x16_bf16(av, bv, m, 0, 0, 0);
        }
        const int a_i = ad >> 2, d_i = ad & 3;
        constexpr float A0[4] = {1.f, 1.f,  1.f,  0.f};
        constexpr float A1[4] = {0.f, 1.f, -1.f, -1.f};
        const float w00 = A0[a_i]*A0[d_i], w01 = A0[a_i]*A1[d_i];
        const float w10 = A1[a_i]*A0[d_i], w11 = A1[a_i]*A1[d_i];
        if (w00 != 0.f) Y00 += w00 * m;     // constant-folded after unroll -> add/sub
        if (w01 != 0.f) Y01 += w01 * m;
        if (w10 != 0.f) Y10 += w10 * m;
        if (w11 != 0.f) Y11 += w11 * m;
    }

    // Epilogue: lane owns k-plane k0+l31; C/D row r -> q = (r&3)+8*(r>>2)+4*q2
    int b = row / 31, p = row % 31;
    int k = k0 + l31;
    float bv = bias[k];
    float* op = out + (size_t)(b*256 + k) * 62 * 62;
    #pragma unroll
    for (int r = 0; r < 16; ++r) {
        int q = (r & 3) + 8*(r >> 2) + 4*q2;
        if (q < 31) {
            float2 v0 = make_float2(Y00[r] + bv, Y01[r] + bv);
            float2 v1 = make_float2(Y10[r] + bv, Y11[r] + bv);
            *(float2*)(op + (2*p+0)*62 + 2*q) = v0;
            *(float2*)(op + (2*p+1)*62 + 2*q) = v1;
        }
    }
}

// ---------------------------------------------------------------------------
extern "C" void kernel_launch(void* const* d_in, const int* in_sizes, int n_in,
                              void* d_out, int out_size, void* d_ws, size_t ws_size,
                              hipStream_t stream) {
    const float* x    = (const float*)d_in[0];
    const float* w    = (const float*)d_in[1];
    const float* bias = (const float*)d_in[2];
    float* out = (float*)d_out;

    unsigned short* Up = (unsigned short*)d_ws;        // 16*16*256*8 = 524288 bf16 = 1 MB
    unsigned short* Vp = Up + 524288;                  // 16*16*NP*8 bf16 = ~130 MB

    wino_wtrans<<<dim3(256),       dim3(128), 0, stream>>>(w, Up);
    wino_itrans<<<dim3(NROWS, 16), dim3(256), 0, stream>>>(x, Vp);
    wino_gemm  <<<dim3(NROWS/2, 4),dim3(256), 0, stream>>>(Vp, Up, bias, out);
}